// Round 1
// baseline (407.729 us; speedup 1.0000x reference)
//
#include <hip/hip_runtime.h>
#include <cstddef>

#define NROWS 65536
#define DIN   512
#define ZDIM  128
#define KCB   1024

// ---------------------------------------------------------------------------
// K1: z = x @ W + b   (f32, BM=64 x BN=128, BK=32)
// 256 threads: tx = t&15 (col group, cols {tx*4..+3, 64+tx*4..+3}),
//              ty = t>>4 (row group, rows ty*4..+3). 32 f32 acc / thread.
// ---------------------------------------------------------------------------
__global__ __launch_bounds__(256) void k1_gemm(
    const float* __restrict__ x, const float* __restrict__ W,
    const float* __restrict__ b, float* __restrict__ z)
{
  __shared__ float xs[32][68];    // transposed x tile: xs[kk][row]
  __shared__ float ws[32][132];   // W tile: ws[kk][col]

  const int t  = threadIdx.x;
  const int tx = t & 15, ty = t >> 4;
  const int bm = blockIdx.x;

  float acc[4][8];
#pragma unroll
  for (int i = 0; i < 4; ++i)
#pragma unroll
    for (int j = 0; j < 8; ++j) acc[i][j] = 0.f;

  const int sr  = t >> 2;          // staging row 0..63
  const int skb = (t & 3) * 8;     // staging k base (0,8,16,24)
  const int wkk = t >> 3;          // 0..31
  const int wcol = (t & 7) * 16;   // 0..112

  for (int k0 = 0; k0 < DIN; k0 += 32) {
    // stage x (64 rows x 32 k), transposed into LDS
    float4 v0 = *reinterpret_cast<const float4*>(&x[(size_t)(bm * 64 + sr) * DIN + k0 + skb]);
    float4 v1 = *reinterpret_cast<const float4*>(&x[(size_t)(bm * 64 + sr) * DIN + k0 + skb + 4]);
    xs[skb + 0][sr] = v0.x; xs[skb + 1][sr] = v0.y; xs[skb + 2][sr] = v0.z; xs[skb + 3][sr] = v0.w;
    xs[skb + 4][sr] = v1.x; xs[skb + 5][sr] = v1.y; xs[skb + 6][sr] = v1.z; xs[skb + 7][sr] = v1.w;
    // stage W (32 k x 128 cols)
#pragma unroll
    for (int u = 0; u < 4; ++u) {
      float4 wv = *reinterpret_cast<const float4*>(&W[(size_t)(k0 + wkk) * ZDIM + wcol + u * 4]);
      *reinterpret_cast<float4*>(&ws[wkk][wcol + u * 4]) = wv;
    }
    __syncthreads();
#pragma unroll
    for (int kk = 0; kk < 32; ++kk) {
      float4 xv = *reinterpret_cast<float4*>(&xs[kk][ty * 4]);
      float4 wa = *reinterpret_cast<float4*>(&ws[kk][tx * 4]);
      float4 wb = *reinterpret_cast<float4*>(&ws[kk][64 + tx * 4]);
      float xr[4] = {xv.x, xv.y, xv.z, xv.w};
      float wr[8] = {wa.x, wa.y, wa.z, wa.w, wb.x, wb.y, wb.z, wb.w};
#pragma unroll
      for (int i = 0; i < 4; ++i)
#pragma unroll
        for (int j = 0; j < 8; ++j) acc[i][j] += xr[i] * wr[j];
    }
    __syncthreads();
  }

  float4 ba = *reinterpret_cast<const float4*>(&b[tx * 4]);
  float4 bb = *reinterpret_cast<const float4*>(&b[64 + tx * 4]);
#pragma unroll
  for (int i = 0; i < 4; ++i) {
    size_t row = (size_t)bm * 64 + ty * 4 + i;
    float4 oa = {acc[i][0] + ba.x, acc[i][1] + ba.y, acc[i][2] + ba.z, acc[i][3] + ba.w};
    float4 ob = {acc[i][4] + bb.x, acc[i][5] + bb.y, acc[i][6] + bb.z, acc[i][7] + bb.w};
    *reinterpret_cast<float4*>(&z[row * ZDIM + tx * 4]) = oa;
    *reinterpret_cast<float4*>(&z[row * ZDIM + 64 + tx * 4]) = ob;
  }
}

// ---------------------------------------------------------------------------
// K2: distances + argmin + all outputs, fused.
// Per block: 64 rows of z vs all 1024 codebook entries.
// sq = (||z||^2 - 2*(z.c)) + ||c||^2  -- same association as the reference.
// ---------------------------------------------------------------------------
__global__ __launch_bounds__(256) void k2_vq(
    const float* __restrict__ zc, const float* __restrict__ cbk,
    float* __restrict__ zst, float* __restrict__ zq, float* __restrict__ oh)
{
  __shared__ float zt[128][68];    // transposed z tile: zt[k][row]
  __shared__ float ct[32][132];    // transposed codebook sub-tile: ct[k][col]
  __shared__ float pc[128][2];     // codebook-norm partials
  __shared__ float csqc[128];      // ||c||^2 for current 128-col chunk
  __shared__ float Ap[64][4];      // ||z||^2 partials
  __shared__ float Al[64];         // ||z||^2 per row
  __shared__ float fbuf[64][17];
  __shared__ int   ibuf[64][17];
  __shared__ int   karr[64];

  const int t  = threadIdx.x;
  const int tx = t & 15, ty = t >> 4;
  const int bm = blockIdx.x;

  // ---- stage z (64 x 128) transposed; accumulate ||z||^2 partials ----
  {
    const int r = t >> 2, kb = (t & 3) * 32;
    float asum = 0.f;
#pragma unroll
    for (int u = 0; u < 8; ++u) {
      float4 v = *reinterpret_cast<const float4*>(&zc[(size_t)(bm * 64 + r) * ZDIM + kb + u * 4]);
      zt[kb + u * 4 + 0][r] = v.x; zt[kb + u * 4 + 1][r] = v.y;
      zt[kb + u * 4 + 2][r] = v.z; zt[kb + u * 4 + 3][r] = v.w;
      asum += v.x * v.x + v.y * v.y + v.z * v.z + v.w * v.w;
    }
    Ap[r][t & 3] = asum;
  }
  __syncthreads();
  if (t < 64) Al[t] = (Ap[t][0] + Ap[t][1]) + (Ap[t][2] + Ap[t][3]);

  float fmin[4];
  int   kmin[4];
#pragma unroll
  for (int i = 0; i < 4; ++i) { fmin[i] = 3.4e38f; kmin[i] = 0; }

  const int scol = t >> 1, skb = (t & 1) * 16;

  for (int chunk = 0; chunk < 8; ++chunk) {
    float acc[4][8];
#pragma unroll
    for (int i = 0; i < 4; ++i)
#pragma unroll
      for (int j = 0; j < 8; ++j) acc[i][j] = 0.f;
    float cpart = 0.f;

    for (int ks = 0; ks < 4; ++ks) {
      __syncthreads();  // previous ct readers done
#pragma unroll
      for (int u = 0; u < 4; ++u) {
        float4 v = *reinterpret_cast<const float4*>(
            &cbk[(size_t)(chunk * 128 + scol) * ZDIM + ks * 32 + skb + u * 4]);
        ct[skb + u * 4 + 0][scol] = v.x; ct[skb + u * 4 + 1][scol] = v.y;
        ct[skb + u * 4 + 2][scol] = v.z; ct[skb + u * 4 + 3][scol] = v.w;
        cpart += v.x * v.x + v.y * v.y + v.z * v.z + v.w * v.w;
      }
      __syncthreads();
#pragma unroll
      for (int kk = 0; kk < 32; ++kk) {
        float4 xv = *reinterpret_cast<float4*>(&zt[ks * 32 + kk][ty * 4]);
        float4 wa = *reinterpret_cast<float4*>(&ct[kk][tx * 4]);
        float4 wb = *reinterpret_cast<float4*>(&ct[kk][64 + tx * 4]);
        float xr[4] = {xv.x, xv.y, xv.z, xv.w};
        float wr[8] = {wa.x, wa.y, wa.z, wa.w, wb.x, wb.y, wb.z, wb.w};
#pragma unroll
        for (int i = 0; i < 4; ++i)
#pragma unroll
          for (int j = 0; j < 8; ++j) acc[i][j] += xr[i] * wr[j];
      }
    }

    // combine ||c||^2 for this chunk
    pc[scol][t & 1] = cpart;
    __syncthreads();
    if (t < 128) csqc[t] = pc[t][0] + pc[t][1];
    __syncthreads();

    // running argmin update (first-index tie-break)
#pragma unroll
    for (int i = 0; i < 4; ++i) {
      float Ar = Al[ty * 4 + i];
#pragma unroll
      for (int j = 0; j < 8; ++j) {
        int colL = (j < 4) ? (tx * 4 + j) : (64 + tx * 4 + (j - 4));
        float B = 2.f * acc[i][j];          // exact (x2)
        float f = (Ar - B) + csqc[colL];    // same association as reference
        int col = chunk * 128 + colL;
        if (f < fmin[i] || (f == fmin[i] && col < kmin[i])) { fmin[i] = f; kmin[i] = col; }
      }
    }
  }

  // ---- cross-thread reduce (16 col-groups per row) ----
#pragma unroll
  for (int i = 0; i < 4; ++i) { fbuf[ty * 4 + i][tx] = fmin[i]; ibuf[ty * 4 + i][tx] = kmin[i]; }
  __syncthreads();
  if (t < 64) {
    float bf = fbuf[t][0]; int bi = ibuf[t][0];
    for (int e = 1; e < 16; ++e) {
      float f2 = fbuf[t][e]; int i2 = ibuf[t][e];
      if (f2 < bf || (f2 == bf && i2 < bi)) { bf = f2; bi = i2; }
    }
    karr[t] = bi;
  }
  __syncthreads();

  // ---- z_quantised + z_straight_through (numerically identical forward) ----
  for (int it = 0; it < 32; ++it) {
    int r = it * 2 + (t >> 7);
    int col = t & 127;
    size_t row = (size_t)bm * 64 + r;
    float v = cbk[(size_t)karr[r] * ZDIM + col];
    zst[row * ZDIM + col] = v;
    zq[row * ZDIM + col] = v;
  }

  // ---- one_hot: zero + scatter, fused ----
  for (int r = 0; r < 64; ++r) {
    int k = karr[r];
    float4 v = {0.f, 0.f, 0.f, 0.f};
    if ((k >> 2) == t) {
      float* vv = reinterpret_cast<float*>(&v);
      vv[k & 3] = 1.f;
    }
    *reinterpret_cast<float4*>(&oh[(size_t)(bm * 64 + r) * KCB + t * 4]) = v;
  }
}

extern "C" void kernel_launch(void* const* d_in, const int* in_sizes, int n_in,
                              void* d_out, int out_size, void* d_ws, size_t ws_size,
                              hipStream_t stream) {
  const float* x   = (const float*)d_in[0];
  const float* W   = (const float*)d_in[1];
  const float* b   = (const float*)d_in[2];
  const float* cbk = (const float*)d_in[3];

  float* out = (float*)d_out;
  float* zst = out;
  float* zq  = out + (size_t)NROWS * ZDIM;
  float* zc  = out + (size_t)2 * NROWS * ZDIM;
  float* oh  = out + (size_t)3 * NROWS * ZDIM;

  k1_gemm<<<NROWS / 64, 256, 0, stream>>>(x, W, b, zc);
  k2_vq<<<NROWS / 64, 256, 0, stream>>>(zc, cbk, zst, zq, oh);
}

// Round 2
// 279.017 us; speedup vs baseline: 1.4613x; 1.4613x over previous
//
#include <hip/hip_runtime.h>
#include <cstddef>

#define NROWS 65536
#define DIN   512
#define ZDIM  128
#define KCB   1024

typedef float  f32x4  __attribute__((ext_vector_type(4)));
typedef short  short8 __attribute__((ext_vector_type(8)));
typedef short  short4v __attribute__((ext_vector_type(4)));
typedef __bf16 bf16x8 __attribute__((ext_vector_type(8)));
typedef unsigned short ushort_t;
typedef unsigned int   uint_t;

// ws layout: [32 chunks][3 splits][32 cols][256 B swizzled k-row] = 786432 B, then cnorm f32[1024]
#define CHB   24576          // bytes per chunk (32 cols x 3 splits x 256B)
#define SPB   8192           // bytes per split block within chunk
#define WS_CNORM_OFF 786432
#define WS_NEEDED (786432 + 4096)

// ---- exact bf16 3-way split helpers (RTN) ----
__device__ inline ushort_t bf_rtn(float v) {
  uint_t u = __float_as_uint(v);
  uint_t r = (u + 0x7fffu + ((u >> 16) & 1u)) >> 16;
  return (ushort_t)r;
}
__device__ inline float bf_up(ushort_t b) { return __uint_as_float(((uint_t)b) << 16); }

__device__ inline bf16x8 as_bf(short8 s) {
  union { short8 s; bf16x8 b; } u; u.s = s; return u.b;
}

// ---------------------------------------------------------------------------
// K1: z = x @ W + b (f32 VALU, unchanged from round 1 — known good)
// ---------------------------------------------------------------------------
__global__ __launch_bounds__(256) void k1_gemm(
    const float* __restrict__ x, const float* __restrict__ W,
    const float* __restrict__ b, float* __restrict__ z)
{
  __shared__ float xs[32][68];
  __shared__ float ws[32][132];

  const int t  = threadIdx.x;
  const int tx = t & 15, ty = t >> 4;
  const int bm = blockIdx.x;

  float acc[4][8];
#pragma unroll
  for (int i = 0; i < 4; ++i)
#pragma unroll
    for (int j = 0; j < 8; ++j) acc[i][j] = 0.f;

  const int sr  = t >> 2;
  const int skb = (t & 3) * 8;
  const int wkk = t >> 3;
  const int wcol = (t & 7) * 16;

  for (int k0 = 0; k0 < DIN; k0 += 32) {
    float4 v0 = *reinterpret_cast<const float4*>(&x[(size_t)(bm * 64 + sr) * DIN + k0 + skb]);
    float4 v1 = *reinterpret_cast<const float4*>(&x[(size_t)(bm * 64 + sr) * DIN + k0 + skb + 4]);
    xs[skb + 0][sr] = v0.x; xs[skb + 1][sr] = v0.y; xs[skb + 2][sr] = v0.z; xs[skb + 3][sr] = v0.w;
    xs[skb + 4][sr] = v1.x; xs[skb + 5][sr] = v1.y; xs[skb + 6][sr] = v1.z; xs[skb + 7][sr] = v1.w;
#pragma unroll
    for (int u = 0; u < 4; ++u) {
      float4 wv = *reinterpret_cast<const float4*>(&W[(size_t)(k0 + wkk) * ZDIM + wcol + u * 4]);
      *reinterpret_cast<float4*>(&ws[wkk][wcol + u * 4]) = wv;
    }
    __syncthreads();
#pragma unroll
    for (int kk = 0; kk < 32; ++kk) {
      float4 xv = *reinterpret_cast<float4*>(&xs[kk][ty * 4]);
      float4 wa = *reinterpret_cast<float4*>(&ws[kk][tx * 4]);
      float4 wb = *reinterpret_cast<float4*>(&ws[kk][64 + tx * 4]);
      float xr[4] = {xv.x, xv.y, xv.z, xv.w};
      float wr[8] = {wa.x, wa.y, wa.z, wa.w, wb.x, wb.y, wb.z, wb.w};
#pragma unroll
      for (int i = 0; i < 4; ++i)
#pragma unroll
        for (int j = 0; j < 8; ++j) acc[i][j] += xr[i] * wr[j];
    }
    __syncthreads();
  }

  float4 ba = *reinterpret_cast<const float4*>(&b[tx * 4]);
  float4 bb = *reinterpret_cast<const float4*>(&b[64 + tx * 4]);
#pragma unroll
  for (int i = 0; i < 4; ++i) {
    size_t row = (size_t)bm * 64 + ty * 4 + i;
    float4 oa = {acc[i][0] + ba.x, acc[i][1] + ba.y, acc[i][2] + ba.z, acc[i][3] + ba.w};
    float4 ob = {acc[i][4] + bb.x, acc[i][5] + bb.y, acc[i][6] + bb.z, acc[i][7] + bb.w};
    *reinterpret_cast<float4*>(&z[row * ZDIM + tx * 4]) = oa;
    *reinterpret_cast<float4*>(&z[row * ZDIM + 64 + tx * 4]) = ob;
  }
}

// ---------------------------------------------------------------------------
// ksplit: codebook -> 3-way bf16 split in LDS-image layout (+ ||c||^2)
// grid 1024 blocks x 128 threads; block = one codebook row n, thread = k.
// byte within chunk: s*SPB + (n&31)*256 + ((k*2) ^ (((n)&7)<<4))
// ---------------------------------------------------------------------------
__global__ __launch_bounds__(128) void ksplit(
    const float* __restrict__ cbk, char* __restrict__ wsb)
{
  const int n = blockIdx.x, k = threadIdx.x;
  float v = cbk[(size_t)n * ZDIM + k];

  ushort_t s1 = bf_rtn(v);  float f1 = bf_up(s1);
  float r1 = v - f1;        ushort_t s2 = bf_rtn(r1); float f2 = bf_up(s2);
  float r2 = r1 - f2;       ushort_t s3 = bf_rtn(r2);

  const int chunk = n >> 5, nn = n & 31;
  const int kb = (k * 2) ^ ((nn & 7) << 4);
  char* base = wsb + (size_t)chunk * CHB + (size_t)nn * 256;
  *(ushort_t*)(base + 0 * SPB + kb) = s1;
  *(ushort_t*)(base + 1 * SPB + kb) = s2;
  *(ushort_t*)(base + 2 * SPB + kb) = s3;

  // ||c||^2
  float c2 = v * v;
#pragma unroll
  for (int m = 1; m < 64; m <<= 1) c2 += __shfl_xor(c2, m);
  __shared__ float wsum[2];
  if ((threadIdx.x & 63) == 0) wsum[threadIdx.x >> 6] = c2;
  __syncthreads();
  if (threadIdx.x == 0)
    *(float*)(wsb + WS_CNORM_OFF + (size_t)n * 4) = wsum[0] + wsum[1];
}

// ---------------------------------------------------------------------------
// K2 (MFMA): distances via 6-product bf16x3 MFMA + argmin + outputs.
// Block = 256 thr (4 waves), 64 rows; wave w owns rows w*16..+15.
// 32 chunks of 32 codebook cols, double-buffered LDS.
// ---------------------------------------------------------------------------
__global__ __launch_bounds__(256) void k2_mfma(
    const float* __restrict__ zc, const float* __restrict__ cbk,
    const char* __restrict__ cbs, const float* __restrict__ cnorm,
    float* __restrict__ zst, float* __restrict__ zq, float* __restrict__ oh)
{
  __shared__ __align__(16) char smem[2 * CHB];   // also overlaid as z staging (32 KB)
  __shared__ int karr[64];

  const int t = threadIdx.x, w = t >> 6, l = t & 63;
  const int bm = blockIdx.x;

  // ---- Phase A: stage z tile (64 x 128 f32), XOR-swizzled ----
  {
    const int r = t >> 2, kq = (t & 3) * 32;
    const float* src = zc + (size_t)(bm * 64 + r) * ZDIM + kq;
#pragma unroll
    for (int u = 0; u < 8; ++u) {
      f32x4 v = *(const f32x4*)(src + u * 4);
      int byt = ((kq + u * 4) * 4) ^ ((r & 7) << 4);
      *(f32x4*)(smem + r * 512 + byt) = v;
    }
  }
  __syncthreads();

  // ---- Phase B: build A-fragments (bf16x3) + row norms, all in registers ----
  short8 a1[4], a2[4], a3[4];
  float psum = 0.f;
  {
    const int rl = w * 16 + (l & 15), g = l >> 4;
#pragma unroll
    for (int ks = 0; ks < 4; ++ks) {
#pragma unroll
      for (int h = 0; h < 2; ++h) {
        int k0 = 4 * g + 16 * h + 32 * ks;
        f32x4 zv = *(const f32x4*)(smem + rl * 512 + ((k0 * 4) ^ ((rl & 7) << 4)));
#pragma unroll
        for (int j = 0; j < 4; ++j) {
          float v = zv[j];
          ushort_t x1 = bf_rtn(v);  float fa = bf_up(x1);
          float r1 = v - fa;        ushort_t x2 = bf_rtn(r1); float fb = bf_up(x2);
          float r2 = r1 - fb;       ushort_t x3 = bf_rtn(r2);
          a1[ks][h * 4 + j] = (short)x1;
          a2[ks][h * 4 + j] = (short)x2;
          a3[ks][h * 4 + j] = (short)x3;
          psum += v * v;
        }
      }
    }
  }
  // lanes {l, l^16, l^32, l^48} together hold all 128 elems of row w*16+(l&15)
  psum += __shfl_xor(psum, 16);
  psum += __shfl_xor(psum, 32);
  float anorm[4];
#pragma unroll
  for (int i = 0; i < 4; ++i) anorm[i] = __shfl(psum, 4 * (l >> 4) + i);

  __syncthreads();  // z tile reads done; smem becomes B double-buffer

  float fmin[4]; int kmin[4];
#pragma unroll
  for (int i = 0; i < 4; ++i) { fmin[i] = 3.402823466e38f; kmin[i] = 0; }

  // ---- prologue: stage chunk 0 ----
  f32x4 streg[6];
#pragma unroll
  for (int it = 0; it < 6; ++it)
    streg[it] = *(const f32x4*)(cbs + (size_t)0 * CHB + it * 4096 + t * 16);
#pragma unroll
  for (int it = 0; it < 6; ++it)
    *(f32x4*)(smem + it * 4096 + t * 16) = streg[it];
  __syncthreads();

  const int lsw = ((l & 7) << 4);   // read-side swizzle (nn&7 == l&7)

  for (int c = 0; c < 32; ++c) {
    const char* buf = smem + (size_t)(c & 1) * CHB;
    const bool more = (c + 1) < 32;
    if (more) {
#pragma unroll
      for (int it = 0; it < 6; ++it)
        streg[it] = *(const f32x4*)(cbs + (size_t)(c + 1) * CHB + it * 4096 + t * 16);
    }
    float cn0 = cnorm[c * 32 + (l & 15)];
    float cn1 = cnorm[c * 32 + 16 + (l & 15)];

#pragma unroll
    for (int ct = 0; ct < 2; ++ct) {
      f32x4 acc = {0.f, 0.f, 0.f, 0.f};
      const int nn = ct * 16 + (l & 15);
      const char* bp = buf + nn * 256;
#pragma unroll
      for (int ks = 0; ks < 4; ++ks) {
        const int kb = 8 * (l >> 4) + 64 * ks;
        short8 b1, b2, b3;
        {
          short4v lo = *(const short4v*)(bp + 0 * SPB + ((kb) ^ lsw));
          short4v hi = *(const short4v*)(bp + 0 * SPB + ((kb + 32) ^ lsw));
          b1[0]=lo[0];b1[1]=lo[1];b1[2]=lo[2];b1[3]=lo[3];b1[4]=hi[0];b1[5]=hi[1];b1[6]=hi[2];b1[7]=hi[3];
        }
        {
          short4v lo = *(const short4v*)(bp + 1 * SPB + ((kb) ^ lsw));
          short4v hi = *(const short4v*)(bp + 1 * SPB + ((kb + 32) ^ lsw));
          b2[0]=lo[0];b2[1]=lo[1];b2[2]=lo[2];b2[3]=lo[3];b2[4]=hi[0];b2[5]=hi[1];b2[6]=hi[2];b2[7]=hi[3];
        }
        {
          short4v lo = *(const short4v*)(bp + 2 * SPB + ((kb) ^ lsw));
          short4v hi = *(const short4v*)(bp + 2 * SPB + ((kb + 32) ^ lsw));
          b3[0]=lo[0];b3[1]=lo[1];b3[2]=lo[2];b3[3]=lo[3];b3[4]=hi[0];b3[5]=hi[1];b3[6]=hi[2];b3[7]=hi[3];
        }
        acc = __builtin_amdgcn_mfma_f32_16x16x32_bf16(as_bf(a1[ks]), as_bf(b1), acc, 0, 0, 0);
        acc = __builtin_amdgcn_mfma_f32_16x16x32_bf16(as_bf(a1[ks]), as_bf(b2), acc, 0, 0, 0);
        acc = __builtin_amdgcn_mfma_f32_16x16x32_bf16(as_bf(a2[ks]), as_bf(b1), acc, 0, 0, 0);
        acc = __builtin_amdgcn_mfma_f32_16x16x32_bf16(as_bf(a1[ks]), as_bf(b3), acc, 0, 0, 0);
        acc = __builtin_amdgcn_mfma_f32_16x16x32_bf16(as_bf(a2[ks]), as_bf(b2), acc, 0, 0, 0);
        acc = __builtin_amdgcn_mfma_f32_16x16x32_bf16(as_bf(a3[ks]), as_bf(b1), acc, 0, 0, 0);
      }
      const int colbase = c * 32 + ct * 16 + (l & 15);
      const float cn = ct ? cn1 : cn0;
#pragma unroll
      for (int i = 0; i < 4; ++i) {
        float f = (anorm[i] - 2.f * acc[i]) + cn;   // reference's association
        if (f < fmin[i]) { fmin[i] = f; kmin[i] = colbase; }  // ascending cols => first-min kept
      }
    }

    if (more) {
      char* nbuf = smem + (size_t)((c + 1) & 1) * CHB;
#pragma unroll
      for (int it = 0; it < 6; ++it)
        *(f32x4*)(nbuf + it * 4096 + t * 16) = streg[it];
    }
    __syncthreads();
  }

  // ---- cross-lane argmin reduce (16 lanes share the same 4 rows) ----
#pragma unroll
  for (int m = 1; m < 16; m <<= 1) {
#pragma unroll
    for (int i = 0; i < 4; ++i) {
      float f2 = __shfl_xor(fmin[i], m);
      int   k2 = __shfl_xor(kmin[i], m);
      if (f2 < fmin[i] || (f2 == fmin[i] && k2 < kmin[i])) { fmin[i] = f2; kmin[i] = k2; }
    }
  }
  if ((l & 15) == 0) {
#pragma unroll
    for (int i = 0; i < 4; ++i) karr[w * 16 + 4 * (l >> 4) + i] = kmin[i];
  }
  __syncthreads();

  // ---- z_quantised + z_straight_through ----
  for (int it = 0; it < 32; ++it) {
    int r = it * 2 + (t >> 7);
    int col = t & 127;
    size_t row = (size_t)bm * 64 + r;
    float v = cbk[(size_t)karr[r] * ZDIM + col];
    zst[row * ZDIM + col] = v;
    zq[row * ZDIM + col] = v;
  }

  // ---- one_hot ----
  for (int r2 = 0; r2 < 64; ++r2) {
    int k = karr[r2];
    f32x4 v = {0.f, 0.f, 0.f, 0.f};
    if ((k >> 2) == t) v[k & 3] = 1.f;
    *(f32x4*)(oh + (size_t)(bm * 64 + r2) * KCB + t * 4) = v;
  }
}

// ---------------------------------------------------------------------------
// Fallback K2 (round-1 f32 VALU version) if ws is too small.
// ---------------------------------------------------------------------------
__global__ __launch_bounds__(256) void k2_vq(
    const float* __restrict__ zc, const float* __restrict__ cbk,
    float* __restrict__ zst, float* __restrict__ zq, float* __restrict__ oh)
{
  __shared__ float zt[128][68];
  __shared__ float ct[32][132];
  __shared__ float pc[128][2];
  __shared__ float csqc[128];
  __shared__ float Ap[64][4];
  __shared__ float Al[64];
  __shared__ float fbuf[64][17];
  __shared__ int   ibuf[64][17];
  __shared__ int   karr[64];

  const int t  = threadIdx.x;
  const int tx = t & 15, ty = t >> 4;
  const int bm = blockIdx.x;

  {
    const int r = t >> 2, kb = (t & 3) * 32;
    float asum = 0.f;
#pragma unroll
    for (int u = 0; u < 8; ++u) {
      float4 v = *reinterpret_cast<const float4*>(&zc[(size_t)(bm * 64 + r) * ZDIM + kb + u * 4]);
      zt[kb + u * 4 + 0][r] = v.x; zt[kb + u * 4 + 1][r] = v.y;
      zt[kb + u * 4 + 2][r] = v.z; zt[kb + u * 4 + 3][r] = v.w;
      asum += v.x * v.x + v.y * v.y + v.z * v.z + v.w * v.w;
    }
    Ap[r][t & 3] = asum;
  }
  __syncthreads();
  if (t < 64) Al[t] = (Ap[t][0] + Ap[t][1]) + (Ap[t][2] + Ap[t][3]);

  float fmin[4];
  int   kmin[4];
#pragma unroll
  for (int i = 0; i < 4; ++i) { fmin[i] = 3.4e38f; kmin[i] = 0; }

  const int scol = t >> 1, skb = (t & 1) * 16;

  for (int chunk = 0; chunk < 8; ++chunk) {
    float acc[4][8];
#pragma unroll
    for (int i = 0; i < 4; ++i)
#pragma unroll
      for (int j = 0; j < 8; ++j) acc[i][j] = 0.f;
    float cpart = 0.f;

    for (int ks = 0; ks < 4; ++ks) {
      __syncthreads();
#pragma unroll
      for (int u = 0; u < 4; ++u) {
        float4 v = *reinterpret_cast<const float4*>(
            &cbk[(size_t)(chunk * 128 + scol) * ZDIM + ks * 32 + skb + u * 4]);
        ct[skb + u * 4 + 0][scol] = v.x; ct[skb + u * 4 + 1][scol] = v.y;
        ct[skb + u * 4 + 2][scol] = v.z; ct[skb + u * 4 + 3][scol] = v.w;
        cpart += v.x * v.x + v.y * v.y + v.z * v.z + v.w * v.w;
      }
      __syncthreads();
#pragma unroll
      for (int kk = 0; kk < 32; ++kk) {
        float4 xv = *reinterpret_cast<float4*>(&zt[ks * 32 + kk][ty * 4]);
        float4 wa = *reinterpret_cast<float4*>(&ct[kk][tx * 4]);
        float4 wb = *reinterpret_cast<float4*>(&ct[kk][64 + tx * 4]);
        float xr[4] = {xv.x, xv.y, xv.z, xv.w};
        float wr[8] = {wa.x, wa.y, wa.z, wa.w, wb.x, wb.y, wb.z, wb.w};
#pragma unroll
        for (int i = 0; i < 4; ++i)
#pragma unroll
          for (int j = 0; j < 8; ++j) acc[i][j] += xr[i] * wr[j];
      }
    }

    pc[scol][t & 1] = cpart;
    __syncthreads();
    if (t < 128) csqc[t] = pc[t][0] + pc[t][1];
    __syncthreads();

#pragma unroll
    for (int i = 0; i < 4; ++i) {
      float Ar = Al[ty * 4 + i];
#pragma unroll
      for (int j = 0; j < 8; ++j) {
        int colL = (j < 4) ? (tx * 4 + j) : (64 + tx * 4 + (j - 4));
        float B = 2.f * acc[i][j];
        float f = (Ar - B) + csqc[colL];
        int col = chunk * 128 + colL;
        if (f < fmin[i] || (f == fmin[i] && col < kmin[i])) { fmin[i] = f; kmin[i] = col; }
      }
    }
  }

#pragma unroll
  for (int i = 0; i < 4; ++i) { fbuf[ty * 4 + i][tx] = fmin[i]; ibuf[ty * 4 + i][tx] = kmin[i]; }
  __syncthreads();
  if (t < 64) {
    float bf = fbuf[t][0]; int bi = ibuf[t][0];
    for (int e = 1; e < 16; ++e) {
      float f2 = fbuf[t][e]; int i2 = ibuf[t][e];
      if (f2 < bf || (f2 == bf && i2 < bi)) { bf = f2; bi = i2; }
    }
    karr[t] = bi;
  }
  __syncthreads();

  for (int it = 0; it < 32; ++it) {
    int r = it * 2 + (t >> 7);
    int col = t & 127;
    size_t row = (size_t)bm * 64 + r;
    float v = cbk[(size_t)karr[r] * ZDIM + col];
    zst[row * ZDIM + col] = v;
    zq[row * ZDIM + col] = v;
  }

  for (int r = 0; r < 64; ++r) {
    int k = karr[r];
    float4 v = {0.f, 0.f, 0.f, 0.f};
    if ((k >> 2) == t) {
      float* vv = reinterpret_cast<float*>(&v);
      vv[k & 3] = 1.f;
    }
    *reinterpret_cast<float4*>(&oh[(size_t)(bm * 64 + r) * KCB + t * 4]) = v;
  }
}

extern "C" void kernel_launch(void* const* d_in, const int* in_sizes, int n_in,
                              void* d_out, int out_size, void* d_ws, size_t ws_size,
                              hipStream_t stream) {
  const float* x   = (const float*)d_in[0];
  const float* W   = (const float*)d_in[1];
  const float* b   = (const float*)d_in[2];
  const float* cbk = (const float*)d_in[3];

  float* out = (float*)d_out;
  float* zst = out;
  float* zq  = out + (size_t)NROWS * ZDIM;
  float* zc  = out + (size_t)2 * NROWS * ZDIM;
  float* oh  = out + (size_t)3 * NROWS * ZDIM;

  k1_gemm<<<NROWS / 64, 256, 0, stream>>>(x, W, b, zc);

  if (ws_size >= (size_t)WS_NEEDED) {
    ksplit<<<KCB, 128, 0, stream>>>(cbk, (char*)d_ws);
    k2_mfma<<<NROWS / 64, 256, 0, stream>>>(
        zc, cbk, (const char*)d_ws,
        (const float*)((const char*)d_ws + WS_CNORM_OFF), zst, zq, oh);
  } else {
    k2_vq<<<NROWS / 64, 256, 0, stream>>>(zc, cbk, zst, zq, oh);
  }
}

// Round 3
// 169.005 us; speedup vs baseline: 2.4125x; 1.6509x over previous
//
#include <hip/hip_runtime.h>
#include <cstddef>

#define NROWS 65536
#define DIN   512
#define ZDIM  128
#define KCB   1024

typedef float  f32x4  __attribute__((ext_vector_type(4)));
typedef short  short8 __attribute__((ext_vector_type(8)));
typedef __bf16 bf16x8 __attribute__((ext_vector_type(8)));
typedef unsigned short ushort_t;
typedef unsigned int   uint_t;

// ---- ws layout ----
// codebook frags: [32 chunks][3 s][2 ct][4 ks][1024 B]  = 786432 B
// cnorm f32[1024]                                        = 4096 B
// W frags:        [16 kc][3 s][8 ct][1024 B]             = 393216 B
#define CB_CHB 24576
#define CB_SPB 8192
#define W_CHB  24576
#define W_SPB  8192
#define CNORM_OFF 786432
#define WF_OFF    790528
#define WS_NEEDED (790528 + 393216)

// ---- exact bf16 3-way split helpers (RTN) ----
__device__ inline ushort_t bf_rtn(float v) {
  uint_t u = __float_as_uint(v);
  uint_t r = (u + 0x7fffu + ((u >> 16) & 1u)) >> 16;
  return (ushort_t)r;
}
__device__ inline float bf_up(ushort_t b) { return __uint_as_float(((uint_t)b) << 16); }
__device__ inline bf16x8 as_bf(short8 s) {
  union { short8 s; bf16x8 b; } u; u.s = s; return u.b;
}
__device__ inline void split3(float v, ushort_t& s1, ushort_t& s2, ushort_t& s3) {
  s1 = bf_rtn(v);  float f1 = bf_up(s1);
  float r1 = v - f1; s2 = bf_rtn(r1); float f2 = bf_up(s2);
  float r2 = r1 - f2; s3 = bf_rtn(r2);
}

// ---------------------------------------------------------------------------
// ksplit2: codebook -> fragment-contiguous 3-way bf16 split + ||c||^2
// grid 1024 x 128 (block = codebook row n, thread = k)
// ---------------------------------------------------------------------------
__global__ __launch_bounds__(128) void ksplit2(
    const float* __restrict__ cbk, char* __restrict__ wsb)
{
  const int n = blockIdx.x, k = threadIdx.x;
  float v = cbk[(size_t)n * ZDIM + k];
  ushort_t s1, s2, s3; split3(v, s1, s2, s3);

  const int chunk = n >> 5, ct = (n >> 4) & 1;
  const int km = k & 31, ks = k >> 5;
  const int g = (km >> 2) & 3, h = (km >> 4) & 1, j = (km & 3) + 4 * h;
  const int l = 16 * g + (n & 15);
  char* base = wsb + chunk * CB_CHB + ct * 4096 + ks * 1024 + l * 16 + j * 2;
  *(ushort_t*)(base + 0 * CB_SPB) = s1;
  *(ushort_t*)(base + 1 * CB_SPB) = s2;
  *(ushort_t*)(base + 2 * CB_SPB) = s3;

  float c2 = v * v;
#pragma unroll
  for (int m = 1; m < 64; m <<= 1) c2 += __shfl_xor(c2, m);
  __shared__ float wsum[2];
  if ((threadIdx.x & 63) == 0) wsum[threadIdx.x >> 6] = c2;
  __syncthreads();
  if (threadIdx.x == 0)
    *(float*)(wsb + CNORM_OFF + (size_t)n * 4) = wsum[0] + wsum[1];
}

// ---------------------------------------------------------------------------
// wsplit: W -> fragment-contiguous 3-way bf16 split
// grid 256 x 256; element (k, col)
// ---------------------------------------------------------------------------
__global__ __launch_bounds__(256) void wsplit(
    const float* __restrict__ W, char* __restrict__ wsb)
{
  const int idx = blockIdx.x * 256 + threadIdx.x;     // 0..65535
  const int k = idx >> 7, col = idx & 127;
  float v = W[(size_t)k * ZDIM + col];
  ushort_t s1, s2, s3; split3(v, s1, s2, s3);

  const int kc = k >> 5, km = k & 31;
  const int g = (km >> 2) & 3, h = (km >> 4) & 1, j = (km & 3) + 4 * h;
  const int ct = col >> 4, l = 16 * g + (col & 15);
  char* base = wsb + WF_OFF + kc * W_CHB + ct * 1024 + l * 16 + j * 2;
  *(ushort_t*)(base + 0 * W_SPB) = s1;
  *(ushort_t*)(base + 1 * W_SPB) = s2;
  *(ushort_t*)(base + 2 * W_SPB) = s3;
}

// ---------------------------------------------------------------------------
// k1_mfma: z = x @ W + b via 6-product bf16x3 MFMA. BM=128, 4 waves,
// wave owns 32 rows (2 rowtiles). K chunked by 32 (16 chunks, dbuf LDS).
// ---------------------------------------------------------------------------
__global__ __launch_bounds__(256, 2) void k1_mfma(
    const float* __restrict__ x, const char* __restrict__ wfs,
    const float* __restrict__ b, float* __restrict__ z)
{
  __shared__ __align__(16) char wbuf[2 * W_CHB];   // 48 KB

  const int t = threadIdx.x, w = t >> 6, l = t & 63;
  const int g = l >> 4, c16 = l & 15;
  const int bm = blockIdx.x;

  f32x4 acc[2][8];
#pragma unroll
  for (int rt = 0; rt < 2; ++rt)
#pragma unroll
    for (int ct = 0; ct < 8; ++ct) acc[rt][ct] = (f32x4){0.f, 0.f, 0.f, 0.f};

  const size_t rowb[2] = {
    ((size_t)bm * 128 + w * 32 + 0 * 16 + c16) * DIN,
    ((size_t)bm * 128 + w * 32 + 1 * 16 + c16) * DIN };

  // prologue: stage W chunk 0; issue x loads for kc=0
  f32x4 wreg[6];
#pragma unroll
  for (int it = 0; it < 6; ++it)
    wreg[it] = *(const f32x4*)(wfs + it * 4096 + t * 16);
  f32x4 xcur[2][2];
#pragma unroll
  for (int rt = 0; rt < 2; ++rt)
#pragma unroll
    for (int h = 0; h < 2; ++h)
      xcur[rt][h] = *(const f32x4*)(x + rowb[rt] + 4 * g + 16 * h);
#pragma unroll
  for (int it = 0; it < 6; ++it)
    *(f32x4*)(wbuf + it * 4096 + t * 16) = wreg[it];
  __syncthreads();

  for (int kc = 0; kc < 16; ++kc) {
    const char* buf = wbuf + (size_t)(kc & 1) * W_CHB;
    const bool more = (kc + 1) < 16;
    f32x4 xnext[2][2];
    if (more) {
#pragma unroll
      for (int it = 0; it < 6; ++it)
        wreg[it] = *(const f32x4*)(wfs + (size_t)(kc + 1) * W_CHB + it * 4096 + t * 16);
#pragma unroll
      for (int rt = 0; rt < 2; ++rt)
#pragma unroll
        for (int h = 0; h < 2; ++h)
          xnext[rt][h] = *(const f32x4*)(x + rowb[rt] + (kc + 1) * 32 + 4 * g + 16 * h);
    }

    // convert current x regs -> a-frags
    short8 a1[2], a2[2], a3[2];
#pragma unroll
    for (int rt = 0; rt < 2; ++rt)
#pragma unroll
      for (int h = 0; h < 2; ++h)
#pragma unroll
        for (int j = 0; j < 4; ++j) {
          ushort_t q1, q2, q3; split3(xcur[rt][h][j], q1, q2, q3);
          a1[rt][4 * h + j] = (short)q1;
          a2[rt][4 * h + j] = (short)q2;
          a3[rt][4 * h + j] = (short)q3;
        }

#pragma unroll
    for (int ct = 0; ct < 8; ++ct) {
      const char* bp = buf + ct * 1024 + l * 16;
      short8 b1 = *(const short8*)(bp + 0 * W_SPB);
      short8 b2 = *(const short8*)(bp + 1 * W_SPB);
      short8 b3 = *(const short8*)(bp + 2 * W_SPB);
#pragma unroll
      for (int rt = 0; rt < 2; ++rt) {
        f32x4 a = acc[rt][ct];
        a = __builtin_amdgcn_mfma_f32_16x16x32_bf16(as_bf(a1[rt]), as_bf(b1), a, 0, 0, 0);
        a = __builtin_amdgcn_mfma_f32_16x16x32_bf16(as_bf(a1[rt]), as_bf(b2), a, 0, 0, 0);
        a = __builtin_amdgcn_mfma_f32_16x16x32_bf16(as_bf(a2[rt]), as_bf(b1), a, 0, 0, 0);
        a = __builtin_amdgcn_mfma_f32_16x16x32_bf16(as_bf(a1[rt]), as_bf(b3), a, 0, 0, 0);
        a = __builtin_amdgcn_mfma_f32_16x16x32_bf16(as_bf(a2[rt]), as_bf(b2), a, 0, 0, 0);
        a = __builtin_amdgcn_mfma_f32_16x16x32_bf16(as_bf(a3[rt]), as_bf(b1), a, 0, 0, 0);
        acc[rt][ct] = a;
      }
    }

    if (more) {
      char* nbuf = wbuf + (size_t)((kc + 1) & 1) * W_CHB;
#pragma unroll
      for (int it = 0; it < 6; ++it)
        *(f32x4*)(nbuf + it * 4096 + t * 16) = wreg[it];
#pragma unroll
      for (int rt = 0; rt < 2; ++rt)
#pragma unroll
        for (int h = 0; h < 2; ++h) xcur[rt][h] = xnext[rt][h];
    }
    __syncthreads();
  }

  // epilogue: bias + store
#pragma unroll
  for (int ct = 0; ct < 8; ++ct) {
    float bb = b[ct * 16 + c16];
#pragma unroll
    for (int rt = 0; rt < 2; ++rt)
#pragma unroll
      for (int i = 0; i < 4; ++i) {
        size_t row = (size_t)bm * 128 + w * 32 + rt * 16 + 4 * g + i;
        z[row * ZDIM + ct * 16 + c16] = acc[rt][ct][i] + bb;
      }
  }
}

// ---------------------------------------------------------------------------
// k2_mfma2: distances + argmin + outputs. BM=128 rows, wave owns 32 rows.
// 32 chunks of 32 codebook cols; one-hot zeros overlapped with compute.
// ---------------------------------------------------------------------------
__global__ __launch_bounds__(256, 2) void k2_mfma2(
    const float* __restrict__ zc, const float* __restrict__ cbk,
    const char* __restrict__ cbs, const float* __restrict__ cnorm,
    float* __restrict__ zst, float* __restrict__ zq, float* __restrict__ oh)
{
  __shared__ __align__(16) char buf2[2 * CB_CHB];  // 48 KB
  __shared__ int karr[128];

  const int t = threadIdx.x, w = t >> 6, l = t & 63;
  const int g = l >> 4, c16 = l & 15;
  const int bm = blockIdx.x;

  // issue chunk-0 staging loads first
  f32x4 streg[6];
#pragma unroll
  for (int it = 0; it < 6; ++it)
    streg[it] = *(const f32x4*)(cbs + it * 4096 + t * 16);

  // A-frags + row norms, direct from global zc
  short8 a1[2][4], a2[2][4], a3[2][4];
  float anorm[2][4];
#pragma unroll
  for (int rt = 0; rt < 2; ++rt) {
    const size_t rb = ((size_t)bm * 128 + w * 32 + rt * 16 + c16) * ZDIM;
    float psum = 0.f;
#pragma unroll
    for (int ks = 0; ks < 4; ++ks)
#pragma unroll
      for (int h = 0; h < 2; ++h) {
        f32x4 v = *(const f32x4*)(zc + rb + ks * 32 + 4 * g + 16 * h);
#pragma unroll
        for (int j = 0; j < 4; ++j) {
          ushort_t q1, q2, q3; split3(v[j], q1, q2, q3);
          a1[rt][ks][4 * h + j] = (short)q1;
          a2[rt][ks][4 * h + j] = (short)q2;
          a3[rt][ks][4 * h + j] = (short)q3;
          psum += v[j] * v[j];
        }
      }
    psum += __shfl_xor(psum, 16);
    psum += __shfl_xor(psum, 32);
#pragma unroll
    for (int i = 0; i < 4; ++i) anorm[rt][i] = __shfl(psum, 4 * g + i);
  }

#pragma unroll
  for (int it = 0; it < 6; ++it)
    *(f32x4*)(buf2 + it * 4096 + t * 16) = streg[it];
  __syncthreads();

  float fmin[2][4]; int kmin[2][4];
#pragma unroll
  for (int rt = 0; rt < 2; ++rt)
#pragma unroll
    for (int i = 0; i < 4; ++i) { fmin[rt][i] = 3.402823466e38f; kmin[rt][i] = 0; }

  for (int c = 0; c < 32; ++c) {
    const char* buf = buf2 + (size_t)(c & 1) * CB_CHB;
    const bool more = (c + 1) < 32;
    if (more) {
#pragma unroll
      for (int it = 0; it < 6; ++it)
        streg[it] = *(const f32x4*)(cbs + (size_t)(c + 1) * CB_CHB + it * 4096 + t * 16);
    }

    // overlapped one-hot zero writes: rows c*4 .. c*4+3 of this block
    {
      const size_t orow = (size_t)(bm * 128 + c * 4 + (t >> 6)) * KCB;
#pragma unroll
      for (int u = 0; u < 4; ++u) {
        f32x4 zv = {0.f, 0.f, 0.f, 0.f};
        *(f32x4*)(oh + orow + (t & 63) * 4 + u * 256) = zv;
      }
    }

    float cn0 = cnorm[c * 32 + c16];
    float cn1 = cnorm[c * 32 + 16 + c16];

#pragma unroll
    for (int ct = 0; ct < 2; ++ct) {
      f32x4 pa[2];
#pragma unroll
      for (int rt = 0; rt < 2; ++rt) pa[rt] = (f32x4){0.f, 0.f, 0.f, 0.f};
#pragma unroll
      for (int ks = 0; ks < 4; ++ks) {
        const char* bp = buf + ct * 4096 + ks * 1024 + l * 16;
        short8 b1 = *(const short8*)(bp + 0 * CB_SPB);
        short8 b2 = *(const short8*)(bp + 1 * CB_SPB);
        short8 b3 = *(const short8*)(bp + 2 * CB_SPB);
#pragma unroll
        for (int rt = 0; rt < 2; ++rt) {
          f32x4 a = pa[rt];
          a = __builtin_amdgcn_mfma_f32_16x16x32_bf16(as_bf(a1[rt][ks]), as_bf(b1), a, 0, 0, 0);
          a = __builtin_amdgcn_mfma_f32_16x16x32_bf16(as_bf(a1[rt][ks]), as_bf(b2), a, 0, 0, 0);
          a = __builtin_amdgcn_mfma_f32_16x16x32_bf16(as_bf(a2[rt][ks]), as_bf(b1), a, 0, 0, 0);
          a = __builtin_amdgcn_mfma_f32_16x16x32_bf16(as_bf(a1[rt][ks]), as_bf(b3), a, 0, 0, 0);
          a = __builtin_amdgcn_mfma_f32_16x16x32_bf16(as_bf(a2[rt][ks]), as_bf(b2), a, 0, 0, 0);
          a = __builtin_amdgcn_mfma_f32_16x16x32_bf16(as_bf(a3[rt][ks]), as_bf(b1), a, 0, 0, 0);
          pa[rt] = a;
        }
      }
      const int colb = c * 32 + ct * 16 + c16;
      const float cn = ct ? cn1 : cn0;
#pragma unroll
      for (int rt = 0; rt < 2; ++rt)
#pragma unroll
        for (int i = 0; i < 4; ++i) {
          float f = (anorm[rt][i] - 2.f * pa[rt][i]) + cn;
          if (f < fmin[rt][i]) { fmin[rt][i] = f; kmin[rt][i] = colb; }
        }
    }

    if (more) {
      char* nbuf = buf2 + (size_t)((c + 1) & 1) * CB_CHB;
#pragma unroll
      for (int it = 0; it < 6; ++it)
        *(f32x4*)(nbuf + it * 4096 + t * 16) = streg[it];
    }
    __syncthreads();
  }

  // cross-lane argmin reduce (within 16-lane col groups)
#pragma unroll
  for (int m = 1; m < 16; m <<= 1) {
#pragma unroll
    for (int rt = 0; rt < 2; ++rt)
#pragma unroll
      for (int i = 0; i < 4; ++i) {
        float f2 = __shfl_xor(fmin[rt][i], m);
        int   k2 = __shfl_xor(kmin[rt][i], m);
        if (f2 < fmin[rt][i] || (f2 == fmin[rt][i] && k2 < kmin[rt][i])) {
          fmin[rt][i] = f2; kmin[rt][i] = k2;
        }
      }
  }
  if (c16 == 0) {
#pragma unroll
    for (int rt = 0; rt < 2; ++rt)
#pragma unroll
      for (int i = 0; i < 4; ++i)
        karr[w * 32 + rt * 16 + 4 * g + i] = kmin[rt][i];
  }
  __syncthreads();

  // z_quantised + z_straight_through
  for (int it = 0; it < 64; ++it) {
    int r = it * 2 + (t >> 7);
    int col = t & 127;
    size_t row = (size_t)bm * 128 + r;
    float v = cbk[(size_t)karr[r] * ZDIM + col];
    zst[row * ZDIM + col] = v;
    zq[row * ZDIM + col] = v;
  }

  // one-hot scatter of the 1.0s (zeros already written during chunk loop)
  if (t < 128) {
    oh[(size_t)(bm * 128 + t) * KCB + karr[t]] = 1.0f;
  }
}

// ---------------------------------------------------------------------------
// Fallback path (ws too small): round-1 f32 kernels
// ---------------------------------------------------------------------------
__global__ __launch_bounds__(256) void k1_gemm(
    const float* __restrict__ x, const float* __restrict__ W,
    const float* __restrict__ b, float* __restrict__ z)
{
  __shared__ float xs[32][68];
  __shared__ float ws[32][132];

  const int t  = threadIdx.x;
  const int tx = t & 15, ty = t >> 4;
  const int bm = blockIdx.x;

  float acc[4][8];
#pragma unroll
  for (int i = 0; i < 4; ++i)
#pragma unroll
    for (int j = 0; j < 8; ++j) acc[i][j] = 0.f;

  const int sr  = t >> 2;
  const int skb = (t & 3) * 8;
  const int wkk = t >> 3;
  const int wcol = (t & 7) * 16;

  for (int k0 = 0; k0 < DIN; k0 += 32) {
    float4 v0 = *reinterpret_cast<const float4*>(&x[(size_t)(bm * 64 + sr) * DIN + k0 + skb]);
    float4 v1 = *reinterpret_cast<const float4*>(&x[(size_t)(bm * 64 + sr) * DIN + k0 + skb + 4]);
    xs[skb + 0][sr] = v0.x; xs[skb + 1][sr] = v0.y; xs[skb + 2][sr] = v0.z; xs[skb + 3][sr] = v0.w;
    xs[skb + 4][sr] = v1.x; xs[skb + 5][sr] = v1.y; xs[skb + 6][sr] = v1.z; xs[skb + 7][sr] = v1.w;
#pragma unroll
    for (int u = 0; u < 4; ++u) {
      float4 wv = *reinterpret_cast<const float4*>(&W[(size_t)(k0 + wkk) * ZDIM + wcol + u * 4]);
      *reinterpret_cast<float4*>(&ws[wkk][wcol + u * 4]) = wv;
    }
    __syncthreads();
#pragma unroll
    for (int kk = 0; kk < 32; ++kk) {
      float4 xv = *reinterpret_cast<float4*>(&xs[kk][ty * 4]);
      float4 wa = *reinterpret_cast<float4*>(&ws[kk][tx * 4]);
      float4 wb = *reinterpret_cast<float4*>(&ws[kk][64 + tx * 4]);
      float xr[4] = {xv.x, xv.y, xv.z, xv.w};
      float wr[8] = {wa.x, wa.y, wa.z, wa.w, wb.x, wb.y, wb.z, wb.w};
#pragma unroll
      for (int i = 0; i < 4; ++i)
#pragma unroll
        for (int j = 0; j < 8; ++j) acc[i][j] += xr[i] * wr[j];
    }
    __syncthreads();
  }

  float4 ba = *reinterpret_cast<const float4*>(&b[tx * 4]);
  float4 bb = *reinterpret_cast<const float4*>(&b[64 + tx * 4]);
#pragma unroll
  for (int i = 0; i < 4; ++i) {
    size_t row = (size_t)bm * 64 + ty * 4 + i;
    float4 oa = {acc[i][0] + ba.x, acc[i][1] + ba.y, acc[i][2] + ba.z, acc[i][3] + ba.w};
    float4 ob = {acc[i][4] + bb.x, acc[i][5] + bb.y, acc[i][6] + bb.z, acc[i][7] + bb.w};
    *reinterpret_cast<float4*>(&z[row * ZDIM + tx * 4]) = oa;
    *reinterpret_cast<float4*>(&z[row * ZDIM + 64 + tx * 4]) = ob;
  }
}

__global__ __launch_bounds__(256) void k2_vq(
    const float* __restrict__ zc, const float* __restrict__ cbk,
    float* __restrict__ zst, float* __restrict__ zq, float* __restrict__ oh)
{
  __shared__ float zt[128][68];
  __shared__ float ct[32][132];
  __shared__ float pc[128][2];
  __shared__ float csqc[128];
  __shared__ float Ap[64][4];
  __shared__ float Al[64];
  __shared__ float fbuf[64][17];
  __shared__ int   ibuf[64][17];
  __shared__ int   karr[64];

  const int t  = threadIdx.x;
  const int tx = t & 15, ty = t >> 4;
  const int bm = blockIdx.x;

  {
    const int r = t >> 2, kb = (t & 3) * 32;
    float asum = 0.f;
#pragma unroll
    for (int u = 0; u < 8; ++u) {
      float4 v = *reinterpret_cast<const float4*>(&zc[(size_t)(bm * 64 + r) * ZDIM + kb + u * 4]);
      zt[kb + u * 4 + 0][r] = v.x; zt[kb + u * 4 + 1][r] = v.y;
      zt[kb + u * 4 + 2][r] = v.z; zt[kb + u * 4 + 3][r] = v.w;
      asum += v.x * v.x + v.y * v.y + v.z * v.z + v.w * v.w;
    }
    Ap[r][t & 3] = asum;
  }
  __syncthreads();
  if (t < 64) Al[t] = (Ap[t][0] + Ap[t][1]) + (Ap[t][2] + Ap[t][3]);

  float fmin[4];
  int   kmin[4];
#pragma unroll
  for (int i = 0; i < 4; ++i) { fmin[i] = 3.4e38f; kmin[i] = 0; }

  const int scol = t >> 1, skb = (t & 1) * 16;

  for (int chunk = 0; chunk < 8; ++chunk) {
    float acc[4][8];
#pragma unroll
    for (int i = 0; i < 4; ++i)
#pragma unroll
      for (int j = 0; j < 8; ++j) acc[i][j] = 0.f;
    float cpart = 0.f;

    for (int ks = 0; ks < 4; ++ks) {
      __syncthreads();
#pragma unroll
      for (int u = 0; u < 4; ++u) {
        float4 v = *reinterpret_cast<const float4*>(
            &cbk[(size_t)(chunk * 128 + scol) * ZDIM + ks * 32 + skb + u * 4]);
        ct[skb + u * 4 + 0][scol] = v.x; ct[skb + u * 4 + 1][scol] = v.y;
        ct[skb + u * 4 + 2][scol] = v.z; ct[skb + u * 4 + 3][scol] = v.w;
        cpart += v.x * v.x + v.y * v.y + v.z * v.z + v.w * v.w;
      }
      __syncthreads();
#pragma unroll
      for (int kk = 0; kk < 32; ++kk) {
        float4 xv = *reinterpret_cast<float4*>(&zt[ks * 32 + kk][ty * 4]);
        float4 wa = *reinterpret_cast<float4*>(&ct[kk][tx * 4]);
        float4 wb = *reinterpret_cast<float4*>(&ct[kk][64 + tx * 4]);
        float xr[4] = {xv.x, xv.y, xv.z, xv.w};
        float wr[8] = {wa.x, wa.y, wa.z, wa.w, wb.x, wb.y, wb.z, wb.w};
#pragma unroll
        for (int i = 0; i < 4; ++i)
#pragma unroll
          for (int j = 0; j < 8; ++j) acc[i][j] += xr[i] * wr[j];
      }
    }

    pc[scol][t & 1] = cpart;
    __syncthreads();
    if (t < 128) csqc[t] = pc[t][0] + pc[t][1];
    __syncthreads();

#pragma unroll
    for (int i = 0; i < 4; ++i) {
      float Ar = Al[ty * 4 + i];
#pragma unroll
      for (int j = 0; j < 8; ++j) {
        int colL = (j < 4) ? (tx * 4 + j) : (64 + tx * 4 + (j - 4));
        float B = 2.f * acc[i][j];
        float f = (Ar - B) + csqc[colL];
        int col = chunk * 128 + colL;
        if (f < fmin[i] || (f == fmin[i] && col < kmin[i])) { fmin[i] = f; kmin[i] = col; }
      }
    }
  }

#pragma unroll
  for (int i = 0; i < 4; ++i) { fbuf[ty * 4 + i][tx] = fmin[i]; ibuf[ty * 4 + i][tx] = kmin[i]; }
  __syncthreads();
  if (t < 64) {
    float bf = fbuf[t][0]; int bi = ibuf[t][0];
    for (int e = 1; e < 16; ++e) {
      float f2 = fbuf[t][e]; int i2 = ibuf[t][e];
      if (f2 < bf || (f2 == bf && i2 < bi)) { bf = f2; bi = i2; }
    }
    karr[t] = bi;
  }
  __syncthreads();

  for (int it = 0; it < 32; ++it) {
    int r = it * 2 + (t >> 7);
    int col = t & 127;
    size_t row = (size_t)bm * 64 + r;
    float v = cbk[(size_t)karr[r] * ZDIM + col];
    zst[row * ZDIM + col] = v;
    zq[row * ZDIM + col] = v;
  }

  for (int r = 0; r < 64; ++r) {
    int k = karr[r];
    float4 v = {0.f, 0.f, 0.f, 0.f};
    if ((k >> 2) == t) {
      float* vv = reinterpret_cast<float*>(&v);
      vv[k & 3] = 1.f;
    }
    *reinterpret_cast<float4*>(&oh[(size_t)(bm * 64 + r) * KCB + t * 4]) = v;
  }
}

extern "C" void kernel_launch(void* const* d_in, const int* in_sizes, int n_in,
                              void* d_out, int out_size, void* d_ws, size_t ws_size,
                              hipStream_t stream) {
  const float* x   = (const float*)d_in[0];
  const float* W   = (const float*)d_in[1];
  const float* b   = (const float*)d_in[2];
  const float* cbk = (const float*)d_in[3];

  float* out = (float*)d_out;
  float* zst = out;
  float* zq  = out + (size_t)NROWS * ZDIM;
  float* zc  = out + (size_t)2 * NROWS * ZDIM;
  float* oh  = out + (size_t)3 * NROWS * ZDIM;

  if (ws_size >= (size_t)WS_NEEDED) {
    char* wsb = (char*)d_ws;
    ksplit2<<<KCB, 128, 0, stream>>>(cbk, wsb);
    wsplit<<<256, 256, 0, stream>>>(W, wsb);
    k1_mfma<<<NROWS / 128, 256, 0, stream>>>(x, wsb + WF_OFF, b, zc);
    k2_mfma2<<<NROWS / 128, 256, 0, stream>>>(
        zc, cbk, wsb, (const float*)(wsb + CNORM_OFF), zst, zq, oh);
  } else {
    k1_gemm<<<NROWS / 64, 256, 0, stream>>>(x, W, b, zc);
    k2_vq<<<NROWS / 64, 256, 0, stream>>>(zc, cbk, zst, zq, oh);
  }
}